// Round 3
// baseline (671.199 us; speedup 1.0000x reference)
//
#include <hip/hip_runtime.h>

#define B_TOT 4096
#define T_STEPS 512
#define IN 20
#define HID 51

typedef float f32x4 __attribute__((ext_vector_type(4)));
typedef short s16x8 __attribute__((ext_vector_type(8)));

__device__ __forceinline__ unsigned short f2bf(float f) {
    unsigned int u = __float_as_uint(f);
    unsigned int r = (u + 0x7fffu + ((u >> 16) & 1u)) >> 16;
    return (unsigned short)r;
}

__device__ __forceinline__ float fast_rcp(float x) { return __builtin_amdgcn_rcpf(x); }
__device__ __forceinline__ float sigf(float x) { return fast_rcp(1.0f + __expf(-x)); }
__device__ __forceinline__ float tanh_(float x) { return 1.0f - 2.0f * fast_rcp(1.0f + __expf(2.0f * x)); }

// 16 waves: w=0..12 -> L1 tile w (rows = unit_local*4+gate, units 4w..4w+3)
//           w=13    -> L2 tile (rows 0..3 = Wih2 gate rows; K-chunks 1,2 only)
//           w=14,15 -> x stagers (register-pipelined global prefetch, 2 steps deep)
// A = weights (M rows), B = staged data (N = 16 batches).
// D layout: col=lane&15=batch, row-reg = gate -> nonlinearity fully lane-local.

__global__ __launch_bounds__(1024, 1)
void lstm_fused(const float* __restrict__ x,
                const float* __restrict__ Wih1, const float* __restrict__ Whh1,
                const float* __restrict__ bih1, const float* __restrict__ bhh1,
                const float* __restrict__ Wih2, const float* __restrict__ Whh2,
                const float* __restrict__ bih2, const float* __restrict__ bhh2,
                const float* __restrict__ Wmu,  const float* __restrict__ bmu,
                const float* __restrict__ Wlv,  const float* __restrict__ blv,
                float* __restrict__ out)
{
    // B-operand staging, fragment order: [buf][ks][(((k>>3)&3)<<4)|batch][k&7]
    __shared__ __align__(16) unsigned short vA[2][3][64][8];

    const int tid  = threadIdx.x;
    const int lane = tid & 63;
    const int w    = tid >> 6;      // 0..15
    const int bidx = blockIdx.x;

    const int tau = (w < 13) ? w : (w == 13 ? 13 : -1);   // -1 = stager wave
    const bool isL1 = (tau >= 0 && tau < 13);
    const bool isL2 = (tau == 13);

    // ---- gather A-operand weight fragments: A[m=lane&15][k=(lane>>4)*8+j] ----
    s16x8 wfrag[3];
    #pragma unroll
    for (int ks = 0; ks < 3; ++ks) {
        s16x8 f;
        const int m = lane & 15;
        #pragma unroll
        for (int j = 0; j < 8; ++j) {
            int k = ks * 32 + ((lane >> 4) << 3) + j;
            float v = 0.0f;
            if (isL1) {
                int g = m & 3, unit = tau * 4 + (m >> 2);
                if (unit < HID) {
                    int row = g * HID + unit;
                    if (k < IN) v = Wih1[row * IN + k];
                    else if (k >= 32 && k < 32 + HID) v = Whh1[row * HID + (k - 32)];
                }
            } else if (isL2) {
                if (m < 4 && k >= 32 && k < 32 + HID) v = Wih2[m * HID + (k - 32)];
            }
            f[j] = (short)f2bf(v);
        }
        wfrag[ks] = f;
    }

    // bias in accumulator-init layout: reg r = gate r of unit tau*4+(lane>>4)
    f32x4 binit = {0.f, 0.f, 0.f, 0.f};
    if (isL1) {
        int unit = tau * 4 + (lane >> 4);
        if (unit < HID) {
            #pragma unroll
            for (int r = 0; r < 4; ++r) binit[r] = bih1[r * HID + unit] + bhh1[r * HID + unit];
        }
    }
    float whh2g[4];
    if (isL2) {
        #pragma unroll
        for (int r = 0; r < 4; ++r) { whh2g[r] = Whh2[r]; binit[r] = bih2[r] + bhh2[r]; }
    }

    // ---- stager setup: threads of waves 14,15 -> s in [0,128); elems s, s+128, s+256 ----
    const int s = tid - 14 * 64;
    const bool st = (s >= 0);
    int  se[3];  bool sv[3];  const float* sp[3];  int srow[3], sj[3];
    #pragma unroll
    for (int i = 0; i < 3; ++i) {
        se[i] = s + i * 128;
        sv[i] = st && se[i] < 16 * IN;
        if (sv[i]) {
            int b = se[i] / IN, m = se[i] % IN;
            sp[i]   = x + ((size_t)(bidx * 16 + b) * T_STEPS) * IN + m;
            srow[i] = ((m >> 3) & 3) * 16 + b;
            sj[i]   = m & 7;
        } else { sp[i] = x; srow[i] = 0; sj[i] = 0; }
    }

    // ---- zero-init both staging buffers (pads must be exact 0) ----
    {
        unsigned short* vz = &vA[0][0][0][0];
        for (int i = tid; i < 2 * 3 * 64 * 8; i += 1024) vz[i] = 0;
    }
    __syncthreads();
    // stage x_0 directly; prefetch x_1 into regs
    float xr[3] = {0.f, 0.f, 0.f};
    #pragma unroll
    for (int i = 0; i < 3; ++i) if (sv[i]) {
        vA[0][0][srow[i]][sj[i]] = f2bf(sp[i][0]);
        xr[i] = sp[i][(T_STEPS > 1) ? IN : 0];
    }
    __syncthreads();

    float c1 = 0.f;
    float c2p = 0.f, h2p = 0.f, sum2 = 0.f;

    for (int t = 0; t < T_STEPS; ++t) {
        const int p  = t & 1;
        const int pn = p ^ 1;

        if (isL1) {
            s16x8 bf0 = *(const s16x8*)&vA[p][0][lane][0];
            s16x8 bf1 = *(const s16x8*)&vA[p][1][lane][0];
            s16x8 bf2 = *(const s16x8*)&vA[p][2][lane][0];
            f32x4 a = binit;
            a = __builtin_amdgcn_mfma_f32_16x16x32_bf16(wfrag[0], bf0, a, 0, 0, 0);
            a = __builtin_amdgcn_mfma_f32_16x16x32_bf16(wfrag[1], bf1, a, 0, 0, 0);
            a = __builtin_amdgcn_mfma_f32_16x16x32_bf16(wfrag[2], bf2, a, 0, 0, 0);

            float c  = sigf(a[1]) * c1 + sigf(a[0]) * tanh_(a[2]);
            c1 = c;
            float h  = sigf(a[3]) * tanh_(c);
            int unit = tau * 4 + (lane >> 4);
            int k    = 32 + unit;
            int b    = lane & 15;
            vA[pn][k >> 5][(((k >> 3) & 3) << 4) + b][k & 7] = f2bf(h);
        } else if (isL2) {
            // layer-2 gates for step t-1's h1 (which sits in vA[p] at t>0;
            // at t==0 vA[0] h-region is zero -> produces garbage we discard)
            s16x8 bf1 = *(const s16x8*)&vA[p][1][lane][0];
            s16x8 bf2 = *(const s16x8*)&vA[p][2][lane][0];
            f32x4 a = binit;
            a = __builtin_amdgcn_mfma_f32_16x16x32_bf16(wfrag[1], bf1, a, 0, 0, 0);
            a = __builtin_amdgcn_mfma_f32_16x16x32_bf16(wfrag[2], bf2, a, 0, 0, 0);
            if (t > 0 && lane < 16) {
                float pi = a[0] + whh2g[0] * h2p;
                float pf = a[1] + whh2g[1] * h2p;
                float pg = a[2] + whh2g[2] * h2p;
                float po = a[3] + whh2g[3] * h2p;
                float c2 = sigf(pf) * c2p + sigf(pi) * tanh_(pg);
                c2p = c2;
                h2p = sigf(po) * tanh_(c2);
                sum2 += h2p;
            }
        } else {
            // stagers: write x_{t+1} from regs, prefetch x_{t+2}
            const int t2 = (t < T_STEPS - 2) ? t + 2 : T_STEPS - 1;
            #pragma unroll
            for (int i = 0; i < 3; ++i) if (sv[i]) {
                vA[pn][0][srow[i]][sj[i]] = f2bf(xr[i]);
                xr[i] = sp[i][(size_t)t2 * IN];
            }
        }

        __syncthreads();
    }

    // ---- final layer-2 step (t=511): h1_511 sits in vA[0] ----
    if (isL2) {
        s16x8 bf1 = *(const s16x8*)&vA[0][1][lane][0];
        s16x8 bf2 = *(const s16x8*)&vA[0][2][lane][0];
        f32x4 a = binit;
        a = __builtin_amdgcn_mfma_f32_16x16x32_bf16(wfrag[1], bf1, a, 0, 0, 0);
        a = __builtin_amdgcn_mfma_f32_16x16x32_bf16(wfrag[2], bf2, a, 0, 0, 0);
        if (lane < 16) {
            float pi = a[0] + whh2g[0] * h2p;
            float pf = a[1] + whh2g[1] * h2p;
            float pg = a[2] + whh2g[2] * h2p;
            float po = a[3] + whh2g[3] * h2p;
            float c2 = sigf(pf) * c2p + sigf(pi) * tanh_(pg);
            h2p = sigf(po) * tanh_(c2);
            sum2 += h2p;

            // ---- head: (lower, mu, upper, log_var) ----
            float agg = sum2 * (1.0f / 512.0f);
            float mu  = Wmu[0] * agg + bmu[0];
            float lv  = Wlv[0] * agg + blv[0];
            float sg  = __expf(0.5f * lv);
            int bg = bidx * 16 + lane;
            out[bg]             = mu - 1.96f * sg;
            out[B_TOT + bg]     = mu;
            out[2 * B_TOT + bg] = mu + 1.96f * sg;
            out[3 * B_TOT + bg] = lv;
        }
    }
}

extern "C" void kernel_launch(void* const* d_in, const int* in_sizes, int n_in,
                              void* d_out, int out_size, void* d_ws, size_t ws_size,
                              hipStream_t stream) {
    const float* x    = (const float*)d_in[0];
    const float* Wih1 = (const float*)d_in[1];
    const float* Whh1 = (const float*)d_in[2];
    const float* bih1 = (const float*)d_in[3];
    const float* bhh1 = (const float*)d_in[4];
    const float* Wih2 = (const float*)d_in[5];
    const float* Whh2 = (const float*)d_in[6];
    const float* bih2 = (const float*)d_in[7];
    const float* bhh2 = (const float*)d_in[8];
    const float* Wmu  = (const float*)d_in[9];
    const float* bmu  = (const float*)d_in[10];
    const float* Wlv  = (const float*)d_in[11];
    const float* blv  = (const float*)d_in[12];
    float* out = (float*)d_out;

    lstm_fused<<<dim3(B_TOT / 16), dim3(1024), 0, stream>>>(
        x, Wih1, Whh1, bih1, bhh1, Wih2, Whh2, bih2, bhh2, Wmu, bmu, Wlv, blv, out);
}

// Round 4
// 502.861 us; speedup vs baseline: 1.3348x; 1.3348x over previous
//
#include <hip/hip_runtime.h>

#define B_TOT 4096
#define T_STEPS 512
#define IN 20
#define HID 51

typedef float f32x4 __attribute__((ext_vector_type(4)));
typedef short s16x8 __attribute__((ext_vector_type(8)));

__device__ __forceinline__ unsigned short f2bf(float f) {
    unsigned int u = __float_as_uint(f);
    unsigned int r = (u + 0x7fffu + ((u >> 16) & 1u)) >> 16;
    return (unsigned short)r;
}

__device__ __forceinline__ float fast_rcp(float x) { return __builtin_amdgcn_rcpf(x); }
__device__ __forceinline__ float sigf(float x) { return fast_rcp(1.0f + __expf(-x)); }
__device__ __forceinline__ float tanh_(float x) { return 1.0f - 2.0f * fast_rcp(1.0f + __expf(2.0f * x)); }

// 4 waves (1 per SIMD), fat tiles — minimize barrier width & LDS readers:
//   w0: L1 tiles {0,1,2} + x stager (5 elems/lane, register-pipelined)
//   w1: L1 tiles {3,4,5}
//   w2: L1 tiles {6,7,8} + L2 tile (rows 0..3 = Wih2 gates; K-chunks 1,2)
//   w3: L1 tiles {9,10,11,12}
// A = weights (M rows = unit_local*4+gate), B = staged data (N = 16 batches).
// D layout: col=lane&15=batch, reg = gate -> nonlinearity fully lane-local.

__global__ __launch_bounds__(256, 1)
void lstm_fused(const float* __restrict__ x,
                const float* __restrict__ Wih1, const float* __restrict__ Whh1,
                const float* __restrict__ bih1, const float* __restrict__ bhh1,
                const float* __restrict__ Wih2, const float* __restrict__ Whh2,
                const float* __restrict__ bih2, const float* __restrict__ bhh2,
                const float* __restrict__ Wmu,  const float* __restrict__ bmu,
                const float* __restrict__ Wlv,  const float* __restrict__ blv,
                float* __restrict__ out)
{
    // B-operand staging, fragment order: [buf][ks][(((k>>3)&3)<<4)|batch][k&7]
    __shared__ __align__(16) unsigned short vA[2][3][64][8];

    const int tid  = threadIdx.x;
    const int lane = tid & 63;
    const int w    = tid >> 6;      // 0..3
    const int bidx = blockIdx.x;

    const int tbase = (w < 3) ? 3 * w : 9;
    const int ntile = (w < 3) ? 3 : 4;
    const bool isST = (w == 0);     // x stager
    const bool isL2 = (w == 2);     // also runs the layer-2 tile

    // ---- gather A-operand weight fragments: A[m=lane&15][k=(lane>>4)*8+j] ----
    s16x8 wfrag[4][3];
    f32x4 binit[4];
    #pragma unroll
    for (int ti = 0; ti < 4; ++ti) {
        const int tau = tbase + ti;
        const int m = lane & 15;
        const bool act = (ti < ntile);
        #pragma unroll
        for (int ks = 0; ks < 3; ++ks) {
            s16x8 f;
            #pragma unroll
            for (int j = 0; j < 8; ++j) {
                int k = ks * 32 + ((lane >> 4) << 3) + j;
                float v = 0.0f;
                if (act) {
                    int g = m & 3, unit = tau * 4 + (m >> 2);
                    if (unit < HID) {
                        int row = g * HID + unit;
                        if (k < IN) v = Wih1[row * IN + k];
                        else if (k >= 32 && k < 32 + HID) v = Whh1[row * HID + (k - 32)];
                    }
                }
                f[j] = (short)f2bf(v);
            }
            wfrag[ti][ks] = f;
        }
        f32x4 bi = {0.f, 0.f, 0.f, 0.f};
        if (act) {
            int unit = tau * 4 + (lane >> 4);
            if (unit < HID) {
                #pragma unroll
                for (int r = 0; r < 4; ++r) bi[r] = bih1[r * HID + unit] + bhh1[r * HID + unit];
            }
        }
        binit[ti] = bi;
    }

    // ---- layer-2 tile fragments (w2 only): rows 0..3 = Wih2 gates, chunks 1,2 ----
    s16x8 l2frag[2];
    f32x4 l2binit = {0.f, 0.f, 0.f, 0.f};
    float whh2g[4];
    if (isL2) {
        const int m = lane & 15;
        #pragma unroll
        for (int ks = 1; ks < 3; ++ks) {
            s16x8 f;
            #pragma unroll
            for (int j = 0; j < 8; ++j) {
                int k = ks * 32 + ((lane >> 4) << 3) + j;
                float v = 0.0f;
                if (m < 4 && k >= 32 && k < 32 + HID) v = Wih2[m * HID + (k - 32)];
                f[j] = (short)f2bf(v);
            }
            l2frag[ks - 1] = f;
        }
        #pragma unroll
        for (int r = 0; r < 4; ++r) { whh2g[r] = Whh2[r]; l2binit[r] = bih2[r] + bhh2[r]; }
    }

    // ---- x stager setup (w0): 5 elems/lane, e = i*64+lane (320 total, no mask) ----
    const float* sp[5];
    int srow[5], sj[5];
    if (isST) {
        #pragma unroll
        for (int i = 0; i < 5; ++i) {
            int e = i * 64 + lane;
            int b = e / IN, m = e % IN;
            sp[i]   = x + ((size_t)(bidx * 16 + b) * T_STEPS) * IN + m;
            srow[i] = ((m >> 3) & 3) * 16 + b;
            sj[i]   = m & 7;
        }
    }

    // ---- zero-init both staging buffers (pads must stay exact 0 forever) ----
    {
        unsigned short* vz = &vA[0][0][0][0];
        for (int i = tid; i < 2 * 3 * 64 * 8; i += 256) vz[i] = 0;
    }
    __syncthreads();
    float xr[5];
    if (isST) {
        #pragma unroll
        for (int i = 0; i < 5; ++i) {
            vA[0][0][srow[i]][sj[i]] = f2bf(sp[i][0]);   // x_0
            xr[i] = sp[i][IN];                           // prefetch x_1
        }
    }
    __syncthreads();

    float c1[4] = {0.f, 0.f, 0.f, 0.f};
    float c2p = 0.f, h2p = 0.f, sum2 = 0.f;

    for (int t = 0; t < T_STEPS; ++t) {
        const int p  = t & 1;
        const int pn = p ^ 1;

        // shared B fragments
        s16x8 bf0 = *(const s16x8*)&vA[p][0][lane][0];
        s16x8 bf1 = *(const s16x8*)&vA[p][1][lane][0];
        s16x8 bf2 = *(const s16x8*)&vA[p][2][lane][0];

        // ---- L1 tiles ----
        #pragma unroll
        for (int ti = 0; ti < 4; ++ti) {
            if (ti < ntile) {
                f32x4 a = binit[ti];
                a = __builtin_amdgcn_mfma_f32_16x16x32_bf16(wfrag[ti][0], bf0, a, 0, 0, 0);
                a = __builtin_amdgcn_mfma_f32_16x16x32_bf16(wfrag[ti][1], bf1, a, 0, 0, 0);
                a = __builtin_amdgcn_mfma_f32_16x16x32_bf16(wfrag[ti][2], bf2, a, 0, 0, 0);

                float c = sigf(a[1]) * c1[ti] + sigf(a[0]) * tanh_(a[2]);
                c1[ti] = c;
                float h = sigf(a[3]) * tanh_(c);
                int unit = (tbase + ti) * 4 + (lane >> 4);
                int k    = 32 + unit;
                int b    = lane & 15;
                vA[pn][k >> 5][(((k >> 3) & 3) << 4) + b][k & 7] = f2bf(h);
            }
        }

        // ---- layer-2 tile (w2): h1_{t-1} sits in vA[p]; discard t==0 ----
        if (isL2) {
            f32x4 a = l2binit;
            a = __builtin_amdgcn_mfma_f32_16x16x32_bf16(l2frag[0], bf1, a, 0, 0, 0);
            a = __builtin_amdgcn_mfma_f32_16x16x32_bf16(l2frag[1], bf2, a, 0, 0, 0);
            if (t > 0 && lane < 16) {
                float pi = a[0] + whh2g[0] * h2p;
                float pf = a[1] + whh2g[1] * h2p;
                float pg = a[2] + whh2g[2] * h2p;
                float po = a[3] + whh2g[3] * h2p;
                float c2 = sigf(pf) * c2p + sigf(pi) * tanh_(pg);
                c2p = c2;
                h2p = sigf(po) * tanh_(c2);
                sum2 += h2p;
            }
        }

        // ---- x stager (w0): write x_{t+1}, prefetch x_{t+2} ----
        if (isST) {
            const int t2 = (t < T_STEPS - 2) ? t + 2 : T_STEPS - 1;
            #pragma unroll
            for (int i = 0; i < 5; ++i) {
                vA[pn][0][srow[i]][sj[i]] = f2bf(xr[i]);
                xr[i] = sp[i][(size_t)t2 * IN];
            }
        }

        __syncthreads();
    }

    // ---- final layer-2 step: h1_511 sits in vA[0] ----
    if (isL2) {
        s16x8 bf1 = *(const s16x8*)&vA[0][1][lane][0];
        s16x8 bf2 = *(const s16x8*)&vA[0][2][lane][0];
        f32x4 a = l2binit;
        a = __builtin_amdgcn_mfma_f32_16x16x32_bf16(l2frag[0], bf1, a, 0, 0, 0);
        a = __builtin_amdgcn_mfma_f32_16x16x32_bf16(l2frag[1], bf2, a, 0, 0, 0);
        if (lane < 16) {
            float pi = a[0] + whh2g[0] * h2p;
            float pf = a[1] + whh2g[1] * h2p;
            float pg = a[2] + whh2g[2] * h2p;
            float po = a[3] + whh2g[3] * h2p;
            float c2 = sigf(pf) * c2p + sigf(pi) * tanh_(pg);
            h2p = sigf(po) * tanh_(c2);
            sum2 += h2p;

            // ---- head: (lower, mu, upper, log_var) ----
            float agg = sum2 * (1.0f / 512.0f);
            float mu  = Wmu[0] * agg + bmu[0];
            float lv  = Wlv[0] * agg + blv[0];
            float sg  = __expf(0.5f * lv);
            int bg = bidx * 16 + lane;
            out[bg]             = mu - 1.96f * sg;
            out[B_TOT + bg]     = mu;
            out[2 * B_TOT + bg] = mu + 1.96f * sg;
            out[3 * B_TOT + bg] = lv;
        }
    }
}

extern "C" void kernel_launch(void* const* d_in, const int* in_sizes, int n_in,
                              void* d_out, int out_size, void* d_ws, size_t ws_size,
                              hipStream_t stream) {
    const float* x    = (const float*)d_in[0];
    const float* Wih1 = (const float*)d_in[1];
    const float* Whh1 = (const float*)d_in[2];
    const float* bih1 = (const float*)d_in[3];
    const float* bhh1 = (const float*)d_in[4];
    const float* Wih2 = (const float*)d_in[5];
    const float* Whh2 = (const float*)d_in[6];
    const float* bih2 = (const float*)d_in[7];
    const float* bhh2 = (const float*)d_in[8];
    const float* Wmu  = (const float*)d_in[9];
    const float* bmu  = (const float*)d_in[10];
    const float* Wlv  = (const float*)d_in[11];
    const float* blv  = (const float*)d_in[12];
    float* out = (float*)d_out;

    lstm_fused<<<dim3(B_TOT / 16), dim3(256), 0, stream>>>(
        x, Wih1, Whh1, bih1, bhh1, Wih2, Whh2, bih2, bhh2, Wmu, bmu, Wlv, blv, out);
}